// Round 4
// baseline (72.411 us; speedup 1.0000x reference)
//
#include <hip/hip_runtime.h>
#include <math.h>

// Problem constants (from reference): B=8, S=4096, D=1024, fp32 in/out.
#define B_   8
#define S_   4096
#define D_   1024
#define RPW  16                 // rows (seq positions) per wave
#define NPB  (S_ / RPW)         // 256 partials per batch
#define NP   (B_ * NPB)         // 2048 partials total
#define G1   16                 // combine1 groups per batch
#define PPG  (NPB / G1)         // 16 partials per combine1 block

// ws layout (float offsets)
#define PM_OFF    0                       // [NP]   per-wave local max
#define PL_OFF    (PM_OFF + NP)           // [NP]   per-wave local denom
#define M2_OFF    (PL_OFF + NP)           // [B_*G1] group local max
#define L2_OFF    (M2_OFF + B_ * G1)      // [B_*G1] group denom
#define PACC_OFF  16384                   // [NP * D_]   (64KB aligned)
#define ACC2_OFF  (PACC_OFF + NP * D_)    // [B_*G1*D_]

// ---------------------------------------------------------------------------
// Pass 1: one pass over data. Wave owns 16 consecutive rows of one b; lane
// owns 16 columns (4x float4). Explicit A/B register double-buffer keeps the
// next 4-row batch's 16 dwordx4 loads posted during every compute phase.
// R3 lesson: NO pointers-to-local-accumulators (blocked SROA -> 85MB scratch
// spill, VGPR=64). All accumulator updates use compile-time named variables.
// ---------------------------------------------------------------------------
__global__ void attn_pass1(
    const float* __restrict__ data, const float* __restrict__ crit,
    float* __restrict__ pm, float* __restrict__ pl, float* __restrict__ pacc)
{
    const int lane = threadIdx.x & 63;
    const int gw   = blockIdx.x * 4 + (threadIdx.x >> 6);  // 0..NP-1
    const int b    = gw >> 8;                               // / NPB (=256)
    const int pi   = gw & 255;                              // % NPB
    const int s0   = pi * RPW;

    const float4* c4p = reinterpret_cast<const float4*>(crit + (size_t)b * D_);
    float4 cc[4];
    cc[0] = c4p[0 * 64 + lane];
    cc[1] = c4p[1 * 64 + lane];
    cc[2] = c4p[2 * 64 + lane];
    cc[3] = c4p[3 * 64 + lane];

    const float4* dp = reinterpret_cast<const float4*>(data)
                     + (size_t)(b * S_ + s0) * (D_ / 4);

    float4 a0 = {0,0,0,0}, a1 = {0,0,0,0}, a2 = {0,0,0,0}, a3 = {0,0,0,0};
    float m = -INFINITY, l = 0.f;

    float4 vA[4][4], vB[4][4];

    #define LOADG(V, G)                                                        \
        {                                                                      \
            _Pragma("unroll")                                                  \
            for (int r = 0; r < 4; ++r) {                                      \
                const float4* rp = dp + (size_t)((G) * 4 + r) * (D_ / 4);      \
                V[r][0] = rp[0 * 64 + lane];                                   \
                V[r][1] = rp[1 * 64 + lane];                                   \
                V[r][2] = rp[2 * 64 + lane];                                   \
                V[r][3] = rp[3 * 64 + lane];                                   \
            }                                                                  \
        }

    // Accumulator update: direct named variables, compile-time fields only.
    #define UPD1(A, V, J, F)                                                   \
        A.F = fmaf(A.F, scale, fmaf(p0, V[0][J].F, fmaf(p1, V[1][J].F,         \
              fmaf(p2, V[2][J].F, p3 * V[3][J].F))));
    #define UPDA(A, V, J)                                                      \
        UPD1(A, V, J, x) UPD1(A, V, J, y) UPD1(A, V, J, z) UPD1(A, V, J, w)

    // COMPUTE: dot -> pack-4 cross-lane reduce (11 DS ops) -> online softmax.
    #define COMPUTE(V)                                                         \
        {                                                                      \
            float sc[4];                                                       \
            _Pragma("unroll")                                                  \
            for (int r = 0; r < 4; ++r) {                                      \
                float p = 0.f;                                                 \
                _Pragma("unroll")                                              \
                for (int j = 0; j < 4; ++j) {                                  \
                    p = fmaf(V[r][j].x, cc[j].x, p);                           \
                    p = fmaf(V[r][j].y, cc[j].y, p);                           \
                    p = fmaf(V[r][j].z, cc[j].z, p);                           \
                    p = fmaf(V[r][j].w, cc[j].w, p);                           \
                }                                                              \
                sc[r] = p;                                                     \
            }                                                                  \
            /* pack rows 0,1 and 2,3 across xor-1 */                           \
            const bool o1 = (lane & 1);                                        \
            float v01 = o1 ? sc[1] : sc[0], w01 = o1 ? sc[0] : sc[1];          \
            float v23 = o1 ? sc[3] : sc[2], w23 = o1 ? sc[2] : sc[3];          \
            v01 += __shfl_xor(w01, 1, 64);                                     \
            v23 += __shfl_xor(w23, 1, 64);                                     \
            /* pack across xor-2: lane carries row (lane&3) */                 \
            const bool o2 = (lane & 2);                                        \
            float av = o2 ? v23 : v01, bv = o2 ? v01 : v23;                    \
            av += __shfl_xor(bv, 2, 64);                                       \
            /* butterfly over residue class */                                 \
            av += __shfl_xor(av, 4, 64);                                       \
            av += __shfl_xor(av, 8, 64);                                       \
            av += __shfl_xor(av, 16, 64);                                      \
            av += __shfl_xor(av, 32, 64);                                      \
            /* broadcast the 4 row sums to every lane */                       \
            const int base = lane & ~3;                                        \
            const float s0v = __shfl(av, base + 0, 64);                        \
            const float s1v = __shfl(av, base + 1, 64);                        \
            const float s2v = __shfl(av, base + 2, 64);                        \
            const float s3v = __shfl(av, base + 3, 64);                        \
            const float gm = fmaxf(fmaxf(s0v, s1v), fmaxf(s2v, s3v));          \
            const float mn = fmaxf(m, gm);                                     \
            const float scale = __expf(m - mn);                                \
            const float p0 = __expf(s0v - mn);                                 \
            const float p1 = __expf(s1v - mn);                                 \
            const float p2 = __expf(s2v - mn);                                 \
            const float p3 = __expf(s3v - mn);                                 \
            l = fmaf(l, scale, p0 + p1 + p2 + p3);                             \
            UPDA(a0, V, 0) UPDA(a1, V, 1) UPDA(a2, V, 2) UPDA(a3, V, 3)        \
            m = mn;                                                            \
        }

    // Software pipeline over the 4 groups: next batch's loads always posted.
    LOADG(vA, 0)
    LOADG(vB, 1)
    COMPUTE(vA)
    LOADG(vA, 2)
    COMPUTE(vB)
    LOADG(vB, 3)
    COMPUTE(vA)
    COMPUTE(vB)

    #undef LOADG
    #undef COMPUTE
    #undef UPDA
    #undef UPD1

    float4* po = reinterpret_cast<float4*>(pacc) + (size_t)gw * (D_ / 4);
    po[0 * 64 + lane] = a0;
    po[1 * 64 + lane] = a1;
    po[2 * 64 + lane] = a2;
    po[3 * 64 + lane] = a3;
    if (lane == 0) { pm[gw] = m; pl[gw] = l; }
}

// ---------------------------------------------------------------------------
// Combine level 1: block (g, b) merges its 16 partials under the group-LOCAL
// max; global max deferred to combine2.
// ---------------------------------------------------------------------------
__global__ __launch_bounds__(256) void attn_combine1(
    const float* __restrict__ pm, const float* __restrict__ pl,
    const float* __restrict__ pacc, float* __restrict__ acc2,
    float* __restrict__ m2, float* __restrict__ l2)
{
    const int b = blockIdx.y;
    const int g = blockIdx.x;
    const int t = threadIdx.x;
    const int c0 = b * NPB + g * PPG;

    float mloc = -INFINITY;
    #pragma unroll
    for (int k = 0; k < PPG; ++k) mloc = fmaxf(mloc, pm[c0 + k]);

    float4 s = {0,0,0,0};
    float  sl = 0.f;
    #pragma unroll
    for (int k = 0; k < PPG; ++k) {
        const int c = c0 + k;
        const float f = __expf(pm[c] - mloc);
        const float4 v =
            reinterpret_cast<const float4*>(pacc)[(size_t)c * (D_ / 4) + t];
        s.x = fmaf(f, v.x, s.x);
        s.y = fmaf(f, v.y, s.y);
        s.z = fmaf(f, v.z, s.z);
        s.w = fmaf(f, v.w, s.w);
        sl  = fmaf(f, pl[c], sl);
    }
    reinterpret_cast<float4*>(acc2)[(size_t)(b * G1 + g) * (D_ / 4) + t] = s;
    if (t == 0) { m2[b * G1 + g] = mloc; l2[b * G1 + g] = sl; }
}

// ---------------------------------------------------------------------------
// Combine level 2: global max over the 16 group maxima, rescale, sum, divide.
// ---------------------------------------------------------------------------
__global__ __launch_bounds__(256) void attn_combine2(
    const float* __restrict__ acc2, const float* __restrict__ m2,
    const float* __restrict__ l2, float* __restrict__ out)
{
    const int b = blockIdx.x;
    const int t = threadIdx.x;

    float mstar = -INFINITY;
    #pragma unroll
    for (int g = 0; g < G1; ++g) mstar = fmaxf(mstar, m2[b * G1 + g]);

    float L = 0.f;
    float4 s = {0,0,0,0};
    #pragma unroll
    for (int g = 0; g < G1; ++g) {
        const float f = __expf(m2[b * G1 + g] - mstar);
        const float4 v =
            reinterpret_cast<const float4*>(acc2)[(size_t)(b * G1 + g) * (D_ / 4) + t];
        s.x = fmaf(f, v.x, s.x);
        s.y = fmaf(f, v.y, s.y);
        s.z = fmaf(f, v.z, s.z);
        s.w = fmaf(f, v.w, s.w);
        L   = fmaf(f, l2[b * G1 + g], L);
    }
    const float inv = 1.f / L;
    float4 o = { s.x * inv, s.y * inv, s.z * inv, s.w * inv };
    reinterpret_cast<float4*>(out)[(size_t)b * (D_ / 4) + t] = o;
}

extern "C" void kernel_launch(void* const* d_in, const int* in_sizes, int n_in,
                              void* d_out, int out_size, void* d_ws, size_t ws_size,
                              hipStream_t stream)
{
    const float* data = (const float*)d_in[0];   // [B, S, D]
    const float* crit = (const float*)d_in[1];   // [B, D]
    float* ws   = (float*)d_ws;
    float* pm   = ws + PM_OFF;
    float* pl   = ws + PL_OFF;
    float* m2   = ws + M2_OFF;
    float* l2   = ws + L2_OFF;
    float* pacc = ws + PACC_OFF;
    float* acc2 = ws + ACC2_OFF;
    float* out  = (float*)d_out;

    attn_pass1   <<<NP / 4, 256, 0, stream>>>(data, crit, pm, pl, pacc);
    attn_combine1<<<dim3(G1, B_), 256, 0, stream>>>(pm, pl, pacc, acc2, m2, l2);
    attn_combine2<<<B_, 256, 0, stream>>>(acc2, m2, l2, out);
}

// Round 5
// 36.705 us; speedup vs baseline: 1.9728x; 1.9728x over previous
//
#include <hip/hip_runtime.h>
#include <math.h>

// Problem constants (from reference): B=8, S=4096, D=1024, fp32 in/out.
#define B_   8
#define S_   4096
#define D_   1024
#define RPW  16                 // rows (seq positions) per wave
#define NPB  (S_ / RPW)         // 256 partials per batch
#define NP   (B_ * NPB)         // 2048 partials total
#define G1   16                 // combine1 groups per batch
#define PPG  (NPB / G1)         // 16 partials per combine1 block

// ws layout (float offsets)
#define PM_OFF    0                       // [NP]   per-wave local max
#define PL_OFF    (PM_OFF + NP)           // [NP]   per-wave local denom
#define M2_OFF    (PL_OFF + NP)           // [B_*G1] group local max
#define L2_OFF    (M2_OFF + B_ * G1)      // [B_*G1] group denom
#define PACC_OFF  16384                   // [NP * D_]   (64KB aligned)
#define ACC2_OFF  (PACC_OFF + NP * D_)    // [B_*G1*D_]

// ---------------------------------------------------------------------------
// Pass 1: one pass over data. Wave owns 16 consecutive rows of one b; lane
// owns 16 columns (4x float4). Explicit A/B register double-buffer keeps the
// next 4-row batch's 16 dwordx4 loads posted during every compute phase.
//
// R4 lesson: WITHOUT launch_bounds, hipcc's occupancy heuristic clamped the
// kernel to 64 VGPRs and spilled the ~180-reg live set to scratch (~88MB of
// scratch writes, pass1 latency-bound at 2.1 TB/s). launch_bounds(256,2)
// grants a 256-VGPR budget (2 waves/EU min) -> live set fits, no spill.
// ---------------------------------------------------------------------------
__global__ __launch_bounds__(256, 2) void attn_pass1(
    const float* __restrict__ data, const float* __restrict__ crit,
    float* __restrict__ pm, float* __restrict__ pl, float* __restrict__ pacc)
{
    const int lane = threadIdx.x & 63;
    const int gw   = blockIdx.x * 4 + (threadIdx.x >> 6);  // 0..NP-1
    const int b    = gw >> 8;                               // / NPB (=256)
    const int pi   = gw & 255;                              // % NPB
    const int s0   = pi * RPW;

    const float4* c4p = reinterpret_cast<const float4*>(crit + (size_t)b * D_);
    float4 cc[4];
    cc[0] = c4p[0 * 64 + lane];
    cc[1] = c4p[1 * 64 + lane];
    cc[2] = c4p[2 * 64 + lane];
    cc[3] = c4p[3 * 64 + lane];

    const float4* dp = reinterpret_cast<const float4*>(data)
                     + (size_t)(b * S_ + s0) * (D_ / 4);

    float4 a0 = {0,0,0,0}, a1 = {0,0,0,0}, a2 = {0,0,0,0}, a3 = {0,0,0,0};
    float m = -INFINITY, l = 0.f;

    float4 vA[4][4], vB[4][4];

    #define LOADG(V, G)                                                        \
        {                                                                      \
            _Pragma("unroll")                                                  \
            for (int r = 0; r < 4; ++r) {                                      \
                const float4* rp = dp + (size_t)((G) * 4 + r) * (D_ / 4);      \
                V[r][0] = rp[0 * 64 + lane];                                   \
                V[r][1] = rp[1 * 64 + lane];                                   \
                V[r][2] = rp[2 * 64 + lane];                                   \
                V[r][3] = rp[3 * 64 + lane];                                   \
            }                                                                  \
        }

    // Accumulator update: direct named variables, compile-time fields only.
    #define UPD1(A, V, J, F)                                                   \
        A.F = fmaf(A.F, scale, fmaf(p0, V[0][J].F, fmaf(p1, V[1][J].F,         \
              fmaf(p2, V[2][J].F, p3 * V[3][J].F))));
    #define UPDA(A, V, J)                                                      \
        UPD1(A, V, J, x) UPD1(A, V, J, y) UPD1(A, V, J, z) UPD1(A, V, J, w)

    // COMPUTE: dot -> pack-4 cross-lane reduce (11 DS ops) -> online softmax.
    #define COMPUTE(V)                                                         \
        {                                                                      \
            float sc[4];                                                       \
            _Pragma("unroll")                                                  \
            for (int r = 0; r < 4; ++r) {                                      \
                float p = 0.f;                                                 \
                _Pragma("unroll")                                              \
                for (int j = 0; j < 4; ++j) {                                  \
                    p = fmaf(V[r][j].x, cc[j].x, p);                           \
                    p = fmaf(V[r][j].y, cc[j].y, p);                           \
                    p = fmaf(V[r][j].z, cc[j].z, p);                           \
                    p = fmaf(V[r][j].w, cc[j].w, p);                           \
                }                                                              \
                sc[r] = p;                                                     \
            }                                                                  \
            /* pack rows 0,1 and 2,3 across xor-1 */                           \
            const bool o1 = (lane & 1);                                        \
            float v01 = o1 ? sc[1] : sc[0], w01 = o1 ? sc[0] : sc[1];          \
            float v23 = o1 ? sc[3] : sc[2], w23 = o1 ? sc[2] : sc[3];          \
            v01 += __shfl_xor(w01, 1, 64);                                     \
            v23 += __shfl_xor(w23, 1, 64);                                     \
            /* pack across xor-2: lane carries row (lane&3) */                 \
            const bool o2 = (lane & 2);                                        \
            float av = o2 ? v23 : v01, bv = o2 ? v01 : v23;                    \
            av += __shfl_xor(bv, 2, 64);                                       \
            /* butterfly over residue class */                                 \
            av += __shfl_xor(av, 4, 64);                                       \
            av += __shfl_xor(av, 8, 64);                                       \
            av += __shfl_xor(av, 16, 64);                                      \
            av += __shfl_xor(av, 32, 64);                                      \
            /* broadcast the 4 row sums to every lane */                       \
            const int base = lane & ~3;                                        \
            const float s0v = __shfl(av, base + 0, 64);                        \
            const float s1v = __shfl(av, base + 1, 64);                        \
            const float s2v = __shfl(av, base + 2, 64);                        \
            const float s3v = __shfl(av, base + 3, 64);                        \
            const float gm = fmaxf(fmaxf(s0v, s1v), fmaxf(s2v, s3v));          \
            const float mn = fmaxf(m, gm);                                     \
            const float scale = __expf(m - mn);                                \
            const float p0 = __expf(s0v - mn);                                 \
            const float p1 = __expf(s1v - mn);                                 \
            const float p2 = __expf(s2v - mn);                                 \
            const float p3 = __expf(s3v - mn);                                 \
            l = fmaf(l, scale, p0 + p1 + p2 + p3);                             \
            UPDA(a0, V, 0) UPDA(a1, V, 1) UPDA(a2, V, 2) UPDA(a3, V, 3)        \
            m = mn;                                                            \
        }

    // Software pipeline over the 4 groups: next batch's loads always posted.
    LOADG(vA, 0)
    LOADG(vB, 1)
    COMPUTE(vA)
    LOADG(vA, 2)
    COMPUTE(vB)
    LOADG(vB, 3)
    COMPUTE(vA)
    COMPUTE(vB)

    #undef LOADG
    #undef COMPUTE
    #undef UPDA
    #undef UPD1

    float4* po = reinterpret_cast<float4*>(pacc) + (size_t)gw * (D_ / 4);
    po[0 * 64 + lane] = a0;
    po[1 * 64 + lane] = a1;
    po[2 * 64 + lane] = a2;
    po[3 * 64 + lane] = a3;
    if (lane == 0) { pm[gw] = m; pl[gw] = l; }
}

// ---------------------------------------------------------------------------
// Combine level 1: block (g, b) merges its 16 partials under the group-LOCAL
// max; global max deferred to combine2.
// ---------------------------------------------------------------------------
__global__ __launch_bounds__(256) void attn_combine1(
    const float* __restrict__ pm, const float* __restrict__ pl,
    const float* __restrict__ pacc, float* __restrict__ acc2,
    float* __restrict__ m2, float* __restrict__ l2)
{
    const int b = blockIdx.y;
    const int g = blockIdx.x;
    const int t = threadIdx.x;
    const int c0 = b * NPB + g * PPG;

    float mloc = -INFINITY;
    #pragma unroll
    for (int k = 0; k < PPG; ++k) mloc = fmaxf(mloc, pm[c0 + k]);

    float4 s = {0,0,0,0};
    float  sl = 0.f;
    #pragma unroll
    for (int k = 0; k < PPG; ++k) {
        const int c = c0 + k;
        const float f = __expf(pm[c] - mloc);
        const float4 v =
            reinterpret_cast<const float4*>(pacc)[(size_t)c * (D_ / 4) + t];
        s.x = fmaf(f, v.x, s.x);
        s.y = fmaf(f, v.y, s.y);
        s.z = fmaf(f, v.z, s.z);
        s.w = fmaf(f, v.w, s.w);
        sl  = fmaf(f, pl[c], sl);
    }
    reinterpret_cast<float4*>(acc2)[(size_t)(b * G1 + g) * (D_ / 4) + t] = s;
    if (t == 0) { m2[b * G1 + g] = mloc; l2[b * G1 + g] = sl; }
}

// ---------------------------------------------------------------------------
// Combine level 2: global max over the 16 group maxima, rescale, sum, divide.
// ---------------------------------------------------------------------------
__global__ __launch_bounds__(256) void attn_combine2(
    const float* __restrict__ acc2, const float* __restrict__ m2,
    const float* __restrict__ l2, float* __restrict__ out)
{
    const int b = blockIdx.x;
    const int t = threadIdx.x;

    float mstar = -INFINITY;
    #pragma unroll
    for (int g = 0; g < G1; ++g) mstar = fmaxf(mstar, m2[b * G1 + g]);

    float L = 0.f;
    float4 s = {0,0,0,0};
    #pragma unroll
    for (int g = 0; g < G1; ++g) {
        const float f = __expf(m2[b * G1 + g] - mstar);
        const float4 v =
            reinterpret_cast<const float4*>(acc2)[(size_t)(b * G1 + g) * (D_ / 4) + t];
        s.x = fmaf(f, v.x, s.x);
        s.y = fmaf(f, v.y, s.y);
        s.z = fmaf(f, v.z, s.z);
        s.w = fmaf(f, v.w, s.w);
        L   = fmaf(f, l2[b * G1 + g], L);
    }
    const float inv = 1.f / L;
    float4 o = { s.x * inv, s.y * inv, s.z * inv, s.w * inv };
    reinterpret_cast<float4*>(out)[(size_t)b * (D_ / 4) + t] = o;
}

extern "C" void kernel_launch(void* const* d_in, const int* in_sizes, int n_in,
                              void* d_out, int out_size, void* d_ws, size_t ws_size,
                              hipStream_t stream)
{
    const float* data = (const float*)d_in[0];   // [B, S, D]
    const float* crit = (const float*)d_in[1];   // [B, D]
    float* ws   = (float*)d_ws;
    float* pm   = ws + PM_OFF;
    float* pl   = ws + PL_OFF;
    float* m2   = ws + M2_OFF;
    float* l2   = ws + L2_OFF;
    float* pacc = ws + PACC_OFF;
    float* acc2 = ws + ACC2_OFF;
    float* out  = (float*)d_out;

    attn_pass1   <<<NP / 4, 256, 0, stream>>>(data, crit, pm, pl, pacc);
    attn_combine1<<<dim3(G1, B_), 256, 0, stream>>>(pm, pl, pacc, acc2, m2, l2);
    attn_combine2<<<B_, 256, 0, stream>>>(acc2, m2, l2, out);
}